// Round 5
// baseline (250.916 us; speedup 1.0000x reference)
//
#include <hip/hip_runtime.h>
#include <math.h>

// Rieke cone phototransduction, B=64 T=512 U=1024.
// One thread per (b,u) chain; sequential over T. 65536 threads = 1024 waves
// = 1 wave/SIMD on MI355X (all the parallelism the recurrence admits).

#define TT 512
#define UU 1024
#define UN 16            // register double-buffer depth for X prefetch
#define DTSTEP 0.008f

template <bool FAST>
__device__ __forceinline__ void run_chain(
    const float* __restrict__ xrow, float* __restrict__ orow,
    float sigma, float phi, float eta, float beta, float cgmp2cur,
    float cgmphill, float cdark, float betaSlow, float hillcoef,
    float hillaff, float gam, float gdark)
{
    // Derived constants (one-time, full precision)
    const float darkCurrent = powf(gdark, cgmphill) * cgmp2cur * 0.5f;
    const float gdark_e = powf(2.0f * darkCurrent / cgmp2cur, 1.0f / cgmphill);
    const float cur2ca = beta * cdark / darkCurrent;
    const float smax = eta / phi * gdark_e *
                       (1.0f + powf(cdark / hillaff, hillcoef));

    // Loop-invariant folds
    const float Ar   = 1.0f - DTSTEP * sigma;   // r_n = Ar*r + gamma*x
    const float icd  = 1.0f / cdark;
    const float kc   = cur2ca * cgmp2cur;
    const float iha  = 1.0f / hillaff;
    const float outk = -0.5f * cgmp2cur;
    const float dtbs = DTSTEP * betaSlow;

    // Initial state
    float g  = gdark_e;
    float s  = gdark_e * eta / phi;
    float c  = cdark;
    float cs = cdark;
    float r, p;
    {
        float x0 = xrow[0];
        r = x0 * gam / sigma;
        p = (eta + r) / phi;
    }
    float gp = FAST ? g * g * g : __powf(g, cgmphill);  // g^cgmphill carry

    orow[0] = 0.0f;  // g[:,0,:] stays zero in reference

    auto step = [&](float x, int sidx) {
        float rn  = fmaf(Ar, r, gam * x);
        float pn  = fmaf(DTSTEP, (r + eta) - phi * p, p);
        float den = fmaf(cs, icd, 1.0f);
        float cn  = fmaf(DTSTEP,
                         fmaf(-beta, c, kc * gp * __builtin_amdgcn_rcpf(den)),
                         c);
        float csn = fmaf(-dtbs, cs - c, cs);
        float sn;
        if (FAST) {
            float t2 = cn * iha;
            t2 *= t2;
            sn = smax * __builtin_amdgcn_rcpf(fmaf(t2, t2, 1.0f));
        } else {
            sn = smax / (1.0f + __powf(cn * iha, hillcoef));
        }
        float gn  = fmaf(DTSTEP, fmaf(-p, g, s), g);  // uses OLD s, p
        float gpn = FAST ? gn * gn * gn : __powf(gn, cgmphill);
        __builtin_nontemporal_store(outk * gpn, orow + (sidx + 1) * UU);
        g = gn; s = sn; c = cn; cs = csn; p = pn; r = rn; gp = gpn;
    };

    // Software-pipelined X loads: double-buffered chunks of UN
    float xa[UN], xb[UN];
#pragma unroll
    for (int k = 0; k < UN; ++k) xa[k] = xrow[k * UU];

    int sbase = 0;
    for (int ch = 0; ch < TT / UN - 1; ++ch) {
        const float* nsrc = xrow + (ch + 1) * (UN * UU);
#pragma unroll
        for (int k = 0; k < UN; ++k) xb[k] = nsrc[k * UU];  // prefetch next
#pragma unroll
        for (int k = 0; k < UN; ++k) step(xa[k], sbase + k);
#pragma unroll
        for (int k = 0; k < UN; ++k) xa[k] = xb[k];
        sbase += UN;
    }
    // Final partial chunk: 15 steps -> total steps = 496 + 15 = 511 (t=1..511)
#pragma unroll
    for (int k = 0; k < UN - 1; ++k) step(xa[k], sbase + k);
}

__global__ __launch_bounds__(256, 1) void prfr_kernel(
    const float* __restrict__ X,
    const float* __restrict__ sigma_p, const float* __restrict__ phi_p,
    const float* __restrict__ eta_p,   const float* __restrict__ beta_p,
    const float* __restrict__ cgmp2cur_p, const float* __restrict__ cgmphill_p,
    const float* __restrict__ cdark_p, const float* __restrict__ betaSlow_p,
    const float* __restrict__ hillcoef_p, const float* __restrict__ hillaff_p,
    const float* __restrict__ gamma_p, const float* __restrict__ gdark_p,
    float* __restrict__ out, int total)
{
    const int idx = blockIdx.x * blockDim.x + threadIdx.x;
    if (idx >= total) return;
    const int u = idx & (UU - 1);
    const int b = idx >> 10;

    const float* xrow = X + (long)b * (TT * UU) + u;
    float* orow = out + (long)b * (TT * UU) + u;

    const float sigma = sigma_p[u], phi = phi_p[u], eta = eta_p[u];
    const float beta = beta_p[u], cgmp2cur = cgmp2cur_p[u];
    const float cgmphill = cgmphill_p[u], cdark = cdark_p[u];
    const float betaSlow = betaSlow_p[u], hillcoef = hillcoef_p[u];
    const float hillaff = hillaff_p[u], gam = gamma_p[u], gdark = gdark_p[u];

    if (cgmphill == 3.0f && hillcoef == 4.0f) {
        run_chain<true>(xrow, orow, sigma, phi, eta, beta, cgmp2cur, cgmphill,
                        cdark, betaSlow, hillcoef, hillaff, gam, gdark);
    } else {
        run_chain<false>(xrow, orow, sigma, phi, eta, beta, cgmp2cur, cgmphill,
                         cdark, betaSlow, hillcoef, hillaff, gam, gdark);
    }
}

extern "C" void kernel_launch(void* const* d_in, const int* in_sizes, int n_in,
                              void* d_out, int out_size, void* d_ws, size_t ws_size,
                              hipStream_t stream)
{
    const float* X = (const float*)d_in[0];
    const int B = in_sizes[0] / (TT * UU);
    const int total = B * UU;
    const int block = 256;
    const int grid = (total + block - 1) / block;
    prfr_kernel<<<grid, block, 0, stream>>>(
        X,
        (const float*)d_in[1],  (const float*)d_in[2],  (const float*)d_in[3],
        (const float*)d_in[4],  (const float*)d_in[5],  (const float*)d_in[6],
        (const float*)d_in[7],  (const float*)d_in[8],  (const float*)d_in[9],
        (const float*)d_in[10], (const float*)d_in[11], (const float*)d_in[12],
        (float*)d_out, total);
}